// Round 8
// baseline (509.272 us; speedup 1.0000x reference)
//
#include <hip/hip_runtime.h>
#include <hip/hip_bf16.h>

#define EPS 1e-5f

constexpr int NN = 50000;   // nodes
constexpr int NE = 800000;  // edges

typedef __attribute__((ext_vector_type(8))) __bf16 bf16x8;
typedef __attribute__((ext_vector_type(4))) float f32x4;

// ---------------- utility kernels ----------------
__global__ void memset_i32(int* p, int n) {
  int i = blockIdx.x * blockDim.x + threadIdx.x;
  if (i < n) p[i] = 0;
}

__global__ void deg_kernel(const int* __restrict__ dst, int* __restrict__ degi, int n) {
  int i = blockIdx.x * blockDim.x + threadIdx.x;
  if (i < n) atomicAdd(&degi[dst[i]], 1);
}

__global__ void dinv_kernel(const int* __restrict__ degi, float* __restrict__ dinv, int n) {
  int i = blockIdx.x * blockDim.x + threadIdx.x;
  if (i < n) dinv[i] = rsqrtf((float)(degi[i] + 1));  // +1 self loop
}

// ---------------- scan (row_ptr build) ----------------
__global__ __launch_bounds__(1024) void scan1(const int* __restrict__ cnt,
                                              int* __restrict__ incl,
                                              int* __restrict__ bsum, int n) {
  __shared__ int s[1024];
  int tid = threadIdx.x;
  int i = blockIdx.x * 1024 + tid;
  int v = (i < n) ? cnt[i] : 0;
  s[tid] = v;
  __syncthreads();
  for (int off = 1; off < 1024; off <<= 1) {
    int t = (tid >= off) ? s[tid - off] : 0;
    __syncthreads();
    s[tid] += t;
    __syncthreads();
  }
  if (i < n) incl[i] = s[tid];
  if (tid == 1023) bsum[blockIdx.x] = s[1023];
}

__global__ void scan2(int* __restrict__ bsum, int nb) {
  int lane = threadIdx.x;  // single wave of 64
  int v = (lane < nb) ? bsum[lane] : 0;
  int orig = v;
  for (int off = 1; off < 64; off <<= 1) {
    int t = __shfl_up(v, off, 64);
    if (lane >= off) v += t;
  }
  if (lane < nb) bsum[lane] = v - orig;  // exclusive block offset
}

__global__ __launch_bounds__(1024) void scan3(const int* __restrict__ cnt,
                                              const int* __restrict__ incl,
                                              const int* __restrict__ bsum,
                                              int* __restrict__ rp,
                                              int* __restrict__ cursor, int n) {
  int tid = threadIdx.x;
  int i = blockIdx.x * 1024 + tid;
  if (i < n) {
    int v = incl[i] + bsum[blockIdx.x];
    rp[i + 1] = v;
    cursor[i] = v - cnt[i];
  }
  if (i == 0) rp[0] = 0;
}

__global__ void fill_kernel(const int* __restrict__ src, const int* __restrict__ dst,
                            int* __restrict__ cursor, int* __restrict__ col, int n) {
  int i = blockIdx.x * blockDim.x + threadIdx.x;
  if (i < n) {
    int pos = atomicAdd(&cursor[dst[i]], 1);
    col[pos] = src[i];
  }
}

// ---------------- weight transpose + split into bf16 hi/lo [N][K] ----------------
__global__ void wsplit(const float* __restrict__ W, __bf16* __restrict__ th,
                       __bf16* __restrict__ tl, int K, int N) {
  int i = blockIdx.x * blockDim.x + threadIdx.x;
  if (i >= K * N) return;
  int k = i / N, n = i - k * N;
  float v = W[i];
  __bf16 h = (__bf16)v;
  th[(size_t)n * K + k] = h;
  tl[(size_t)n * K + k] = (__bf16)(v - (float)h);
}

// ---------------- blockify + prescale: x[v][128]*dinv[v] -> Xb[b][v][16] ----------------
__global__ void blockify_scale(const float* __restrict__ x, const float* __restrict__ dinv,
                               float* __restrict__ Xb, int nnodes) {
  int i = blockIdx.x * blockDim.x + threadIdx.x;  // float4 id
  if (i >= nnodes * 32) return;
  int v = i >> 5, f4 = i & 31;
  int f = f4 * 4, b = f >> 4, off = f & 15;
  float4 t = ((const float4*)x)[i];
  float s = dinv[v];
  t.x *= s; t.y *= s; t.z *= s; t.w *= s;
  *(float4*)(Xb + ((size_t)b * nnodes + (size_t)v) * 16 + off) = t;
}

// ---------------- blocked propagation: L2-resident 3.2MB feature blocks ----------------
// grid = (ceil(NN/4), F/16). One wave per node per feature-block.
// Lane = (slot 0..3, j 0..15): 4 edge-slots x 16 features; 16 edges in flight.
// Input Xb already prescaled by dinv[src] (blockify or GEMM epilogue).
// EPI 0: *dinv[v] only; EPI 1: *dinv[v] + bias + BN + ReLU. Output: bf16 hi/lo planes.
template <int F, int EPI>
__global__ __launch_bounds__(256, 8) void prop_blk(
    const float* __restrict__ Xb, const int* __restrict__ rp, const int* __restrict__ col,
    const float* __restrict__ dinv, const float* __restrict__ bias,
    const float* __restrict__ gam, const float* __restrict__ bet,
    const float* __restrict__ mean, const float* __restrict__ var,
    __bf16* __restrict__ out_hi, __bf16* __restrict__ out_lo, int nnodes) {
  int tid = threadIdx.x;
  int wid = tid >> 6, lane = tid & 63;
  int j = lane & 15, slot = lane >> 4;
  int v = blockIdx.x * 4 + wid;
  if (v >= nnodes) return;
  int b = blockIdx.y;
  const float* X = Xb + (size_t)b * nnodes * 16;
  int e0 = rp[v], e1 = rp[v + 1];
  float acc = (slot == 0) ? X[(size_t)v * 16 + j] : 0.f;  // self (prescaled)
  int e1m1 = e1 - 1;
  for (int e = e0; e < e1; e += 16) {
    int ss[4];
    float w[4];
#pragma unroll
    for (int u = 0; u < 4; u++) {
      int idx = e + u * 4 + slot;
      ss[u] = col[idx < e1 ? idx : e1m1];
      w[u] = (idx < e1) ? 1.f : 0.f;
    }
    float vv[4];
#pragma unroll
    for (int u = 0; u < 4; u++) vv[u] = X[(size_t)ss[u] * 16 + j];
#pragma unroll
    for (int u = 0; u < 4; u++) acc = fmaf(vv[u], w[u], acc);
  }
  acc += __shfl_xor(acc, 16);
  acc += __shfl_xor(acc, 32);
  if (slot == 0) {
    int f = b * 16 + j;
    float t = acc * dinv[v];
    if constexpr (EPI >= 1) {
      t += bias[f];
      t = (t - mean[f]) * rsqrtf(var[f] + EPS) * gam[f] + bet[f];
      t = fmaxf(t, 0.f);
    }
    __bf16 h = (__bf16)t;
    out_hi[(size_t)v * F + f] = h;
    out_lo[(size_t)v * F + f] = (__bf16)(t - (float)h);
  }
}

// ---------------- final prop (F=6), linear input ----------------
__global__ __launch_bounds__(256, 8) void prop_small(
    const float* __restrict__ in, const int* __restrict__ rp, const int* __restrict__ col,
    const float* __restrict__ dinv, const float* __restrict__ bias,
    float* __restrict__ out, int nnodes) {
  constexpr int F = 6;
  int tid = threadIdx.x;
  int wid = tid >> 6, lane = tid & 63;
  int g = lane >> 3, f = lane & 7;
  int v = (blockIdx.x * 4 + wid) * 8 + g;
  if (v >= nnodes || f >= F) return;
  int e0 = rp[v], e1 = rp[v + 1];
  float acc = in[(size_t)v * F + f];
  int e1m1 = e1 - 1;
  constexpr int D = 8;
  for (int e = e0; e < e1; e += D) {
    int ss[D];
    float w[D];
#pragma unroll
    for (int u = 0; u < D; u++) {
      int ei = e + u;
      ss[u] = col[ei < e1m1 ? ei : e1m1];
      w[u] = (ei < e1) ? 1.0f : 0.0f;
    }
#pragma unroll
    for (int u = 0; u < D; u++) acc = fmaf(in[(size_t)ss[u] * F + f], w[u], acc);
  }
  out[(size_t)v * F + f] = acc * dinv[v] + bias[f];
}

// ---------------- MFMA GEMM (bf16 split-3), 128xBN tile, 4 waves ----------------
// A as hi/lo planes [M][K]; B as transposed hi/lo planes [N][K].
// EPI 0: +bias, BN, ReLU -> write hi/lo planes.
// EPI 1: *dinv[row] -> write f32; BLOCKED: write Cf[(col/16)][row][col%16].
template <int BN, int EPI, bool BLOCKED>
__global__ __launch_bounds__(256, 4) void mfma_gemm(
    const __bf16* __restrict__ Ahi, const __bf16* __restrict__ Alo,
    const __bf16* __restrict__ Bhi, const __bf16* __restrict__ Blo,
    const float* __restrict__ bias, const float* __restrict__ gam,
    const float* __restrict__ bet, const float* __restrict__ mean,
    const float* __restrict__ var, const float* __restrict__ dinv,
    float* __restrict__ Cf, __bf16* __restrict__ Chi, __bf16* __restrict__ Clo,
    int M, int K, int N) {
  constexpr int BM = 128, BK = 32, NB = BN / 16;
  // +8 bf16 pad (16 B): row stride 80 B spreads b128 frag reads across all 32 banks
  __shared__ __bf16 Ah[BM][BK + 8], Al[BM][BK + 8];
  __shared__ __bf16 Bh[BN][BK + 8], Bl[BN][BK + 8];
  int tid = threadIdx.x;
  int wid = tid >> 6, lane = tid & 63;
  int lr = lane & 15, lg = lane >> 4;
  int bm = blockIdx.x * BM, bn = blockIdx.y * BN;
  f32x4 acc[2][NB] = {};
  for (int k0 = 0; k0 < K; k0 += BK) {
#pragma unroll
    for (int c = 0; c < 2; c++) {  // A tile: 128 rows x 32 bf16, 16B chunks
      int idx = tid + c * 256;
      int r = idx >> 2, s = idx & 3;
      int rg = bm + r;
      uint4 vh = {0, 0, 0, 0}, vl = {0, 0, 0, 0};
      if (rg < M) {
        size_t go = (size_t)rg * K + k0 + s * 8;
        vh = *reinterpret_cast<const uint4*>(Ahi + go);
        vl = *reinterpret_cast<const uint4*>(Alo + go);
      }
      *reinterpret_cast<uint4*>(&Ah[r][s * 8]) = vh;
      *reinterpret_cast<uint4*>(&Al[r][s * 8]) = vl;
    }
#pragma unroll
    for (int c = 0; c < (BN * 4 + 255) / 256; c++) {  // B tile: BN rows x 32 bf16
      int idx = tid + c * 256;
      if (idx < BN * 4) {
        int r = idx >> 2, s = idx & 3;
        int rg = bn + r;
        uint4 vh = {0, 0, 0, 0}, vl = {0, 0, 0, 0};
        if (rg < N) {
          size_t go = (size_t)rg * K + k0 + s * 8;
          vh = *reinterpret_cast<const uint4*>(Bhi + go);
          vl = *reinterpret_cast<const uint4*>(Blo + go);
        }
        *reinterpret_cast<uint4*>(&Bh[r][s * 8]) = vh;
        *reinterpret_cast<uint4*>(&Bl[r][s * 8]) = vl;
      }
    }
    __syncthreads();
    int ar = wid * 32 + lr;
    bf16x8 ah0 = *reinterpret_cast<const bf16x8*>(&Ah[ar][lg * 8]);
    bf16x8 ah1 = *reinterpret_cast<const bf16x8*>(&Ah[ar + 16][lg * 8]);
    bf16x8 al0 = *reinterpret_cast<const bf16x8*>(&Al[ar][lg * 8]);
    bf16x8 al1 = *reinterpret_cast<const bf16x8*>(&Al[ar + 16][lg * 8]);
#pragma unroll
    for (int n = 0; n < NB; n++) {
      bf16x8 bh = *reinterpret_cast<const bf16x8*>(&Bh[n * 16 + lr][lg * 8]);
      bf16x8 bl = *reinterpret_cast<const bf16x8*>(&Bl[n * 16 + lr][lg * 8]);
      acc[0][n] = __builtin_amdgcn_mfma_f32_16x16x32_bf16(ah0, bh, acc[0][n], 0, 0, 0);
      acc[1][n] = __builtin_amdgcn_mfma_f32_16x16x32_bf16(ah1, bh, acc[1][n], 0, 0, 0);
      acc[0][n] = __builtin_amdgcn_mfma_f32_16x16x32_bf16(ah0, bl, acc[0][n], 0, 0, 0);
      acc[1][n] = __builtin_amdgcn_mfma_f32_16x16x32_bf16(ah1, bl, acc[1][n], 0, 0, 0);
      acc[0][n] = __builtin_amdgcn_mfma_f32_16x16x32_bf16(al0, bh, acc[0][n], 0, 0, 0);
      acc[1][n] = __builtin_amdgcn_mfma_f32_16x16x32_bf16(al1, bh, acc[1][n], 0, 0, 0);
    }
    __syncthreads();
  }
  // epilogue: C/D layout col=lane&15, row=(lane>>4)*4+reg (m89-verified)
#pragma unroll
  for (int m = 0; m < 2; m++) {
    int row0 = bm + wid * 32 + m * 16 + lg * 4;
#pragma unroll
    for (int n = 0; n < NB; n++) {
      int colg = bn + n * 16 + lr;
#pragma unroll
      for (int r = 0; r < 4; r++) {
        int row = row0 + r;
        if (row >= M) continue;
        float t = acc[m][n][r];
        if constexpr (EPI == 0) {
          t += bias[colg];
          t = (t - mean[colg]) * rsqrtf(var[colg] + EPS) * gam[colg] + bet[colg];
          t = fmaxf(t, 0.f);
          __bf16 h = (__bf16)t;
          Chi[(size_t)row * N + colg] = h;
          Clo[(size_t)row * N + colg] = (__bf16)(t - (float)h);
        } else if constexpr (BLOCKED) {
          // blocked [col/16][row][col%16], prescaled by dinv[row]
          Cf[((size_t)((bn >> 4) + n) * M + row) * 16 + lr] = t * dinv[row];
        } else {
          if (colg < N) Cf[(size_t)row * N + colg] = t * dinv[row];
        }
      }
    }
  }
}

// ---------------- launch ----------------
extern "C" void kernel_launch(void* const* d_in, const int* in_sizes, int n_in,
                              void* d_out, int out_size, void* d_ws, size_t ws_size,
                              hipStream_t stream) {
  const float* x = (const float*)d_in[0];
  const int* ei = (const int*)d_in[1];
  const int* esrc = ei;
  const int* edst = ei + NE;
  const float* W1 = (const float*)d_in[2];  const float* b1 = (const float*)d_in[3];
  const float* g1 = (const float*)d_in[4];  const float* be1 = (const float*)d_in[5];
  const float* m1 = (const float*)d_in[6];  const float* v1 = (const float*)d_in[7];
  const float* W2 = (const float*)d_in[8];  const float* b2 = (const float*)d_in[9];
  const float* g2 = (const float*)d_in[10]; const float* be2 = (const float*)d_in[11];
  const float* m2 = (const float*)d_in[12]; const float* v2 = (const float*)d_in[13];
  const float* W3 = (const float*)d_in[14]; const float* b3 = (const float*)d_in[15];
  const float* g3 = (const float*)d_in[16]; const float* be3 = (const float*)d_in[17];
  const float* m3 = (const float*)d_in[18]; const float* v3 = (const float*)d_in[19];
  const float* W4 = (const float*)d_in[20]; const float* b4 = (const float*)d_in[21];
  float* out = (float*)d_out;

  // workspace layout
  char* base = (char*)d_ws;
  size_t off = 0;
  auto alloc = [&](size_t bytes) {
    void* p = base + off;
    off = (off + bytes + 255) & ~(size_t)255;
    return p;
  };
  float* Fb = (float*)alloc((size_t)NN * 128 * 4);        // blocked f32 activations (max 128)
  __bf16* PAh = (__bf16*)alloc((size_t)NN * 128 * 2);     // A planes (<=128 cols)
  __bf16* PAl = (__bf16*)alloc((size_t)NN * 128 * 2);
  __bf16* PHh = (__bf16*)alloc((size_t)NN * 256 * 2);     // h planes (<=256 cols)
  __bf16* PHl = (__bf16*)alloc((size_t)NN * 256 * 2);
  __bf16* Wt1h = (__bf16*)alloc(128 * 256 * 2); __bf16* Wt1l = (__bf16*)alloc(128 * 256 * 2);
  __bf16* Wt2h = (__bf16*)alloc(256 * 128 * 2); __bf16* Wt2l = (__bf16*)alloc(256 * 128 * 2);
  __bf16* Wt3h = (__bf16*)alloc(128 * 64 * 2);  __bf16* Wt3l = (__bf16*)alloc(128 * 64 * 2);
  __bf16* Wt4h = (__bf16*)alloc(64 * 6 * 2);    __bf16* Wt4l = (__bf16*)alloc(64 * 6 * 2);
  int* degi = (int*)alloc((size_t)NN * 4);
  float* dinv = (float*)alloc((size_t)NN * 4);
  int* rp = (int*)alloc((size_t)(NN + 1) * 4);
  int* cursor = (int*)alloc((size_t)NN * 4);
  int* incl = (int*)alloc((size_t)NN * 4);
  int* bsum = (int*)alloc(64 * 4);
  int* col = (int*)alloc((size_t)NE * 4);

  const int nBlkN = (NN + 255) / 256;
  const int nBlkE = (NE + 255) / 256;
  const int nBlkScan = (NN + 1023) / 1024;  // 49
  const int gM = (NN + 127) / 128;          // 391
  const int gP = (NN + 3) / 4;              // 12500 (prop_blk x-dim)

  // degree + dinv
  memset_i32<<<nBlkN, 256, 0, stream>>>(degi, NN);
  deg_kernel<<<nBlkE, 256, 0, stream>>>(edst, degi, NE);
  dinv_kernel<<<nBlkN, 256, 0, stream>>>(degi, dinv, NN);

  // CSR build
  scan1<<<nBlkScan, 1024, 0, stream>>>(degi, incl, bsum, NN);
  scan2<<<1, 64, 0, stream>>>(bsum, nBlkScan);
  scan3<<<nBlkScan, 1024, 0, stream>>>(degi, incl, bsum, rp, cursor, NN);
  fill_kernel<<<nBlkE, 256, 0, stream>>>(esrc, edst, cursor, col, NE);

  // weight transpose+split
  wsplit<<<(128 * 256 + 255) / 256, 256, 0, stream>>>(W1, Wt1h, Wt1l, 128, 256);
  wsplit<<<(256 * 128 + 255) / 256, 256, 0, stream>>>(W2, Wt2h, Wt2l, 256, 128);
  wsplit<<<(128 * 64 + 255) / 256, 256, 0, stream>>>(W3, Wt3h, Wt3l, 128, 64);
  wsplit<<<(64 * 6 + 255) / 256, 256, 0, stream>>>(W4, Wt4h, Wt4l, 64, 6);

  // ---- layer 1: blockify+prescale, blocked prop (8 x 3.2MB passes), GEMM1 ----
  blockify_scale<<<(NN * 32 + 255) / 256, 256, 0, stream>>>(x, dinv, Fb, NN);
  {
    dim3 g(gP, 8);
    prop_blk<128, 0><<<g, 256, 0, stream>>>(Fb, rp, col, dinv, nullptr, nullptr, nullptr,
                                            nullptr, nullptr, PAh, PAl, NN);
  }
  {
    dim3 g(gM, 2);
    mfma_gemm<128, 0, false><<<g, 256, 0, stream>>>(PAh, PAl, Wt1h, Wt1l, b1, g1, be1, m1, v1,
                                                    nullptr, nullptr, PHh, PHl, NN, 128, 256);
  }
  // ---- layer 2: GEMM2 (*dinv -> blocked f32), blocked prop (+b2,BN2,ReLU) ----
  {
    dim3 g(gM, 1);
    mfma_gemm<128, 1, true><<<g, 256, 0, stream>>>(PHh, PHl, Wt2h, Wt2l, nullptr, nullptr,
                                                   nullptr, nullptr, nullptr, dinv, Fb,
                                                   nullptr, nullptr, NN, 256, 128);
  }
  {
    dim3 g(gP, 8);
    prop_blk<128, 1><<<g, 256, 0, stream>>>(Fb, rp, col, dinv, b2, g2, be2, m2, v2,
                                            PAh, PAl, NN);
  }
  // ---- layer 3: GEMM3 (*dinv -> blocked f32), blocked prop (+b3,BN3,ReLU) ----
  {
    dim3 g(gM, 1);
    mfma_gemm<64, 1, true><<<g, 256, 0, stream>>>(PAh, PAl, Wt3h, Wt3l, nullptr, nullptr,
                                                  nullptr, nullptr, nullptr, dinv, Fb,
                                                  nullptr, nullptr, NN, 128, 64);
  }
  {
    dim3 g(gP, 4);
    prop_blk<64, 1><<<g, 256, 0, stream>>>(Fb, rp, col, dinv, b3, g3, be3, m3, v3,
                                           PHh, PHl, NN);
  }
  // ---- layer 4: GEMM4 (*dinv -> linear f32, N=6), final prop (+b4) ----
  {
    dim3 g(gM, 1);
    mfma_gemm<16, 1, false><<<g, 256, 0, stream>>>(PHh, PHl, Wt4h, Wt4l, nullptr, nullptr,
                                                   nullptr, nullptr, nullptr, dinv, Fb,
                                                   nullptr, nullptr, NN, 64, 6);
  }
  prop_small<<<(NN + 31) / 32, 256, 0, stream>>>(Fb, rp, col, dinv, b4, out, NN);
}

// Round 9
// 289.521 us; speedup vs baseline: 1.7590x; 1.7590x over previous
//
#include <hip/hip_runtime.h>
#include <hip/hip_bf16.h>
#include <hip/hip_fp16.h>

#define EPS 1e-5f

constexpr int NN = 50000;   // nodes
constexpr int NE = 800000;  // edges

typedef __attribute__((ext_vector_type(8))) __bf16 bf16x8;
typedef __attribute__((ext_vector_type(4))) float f32x4;

// ---------------- utility kernels ----------------
__global__ void memset_i32(int* p, int n) {
  int i = blockIdx.x * blockDim.x + threadIdx.x;
  if (i < n) p[i] = 0;
}

__global__ void deg_kernel(const int* __restrict__ dst, int* __restrict__ degi, int n) {
  int i = blockIdx.x * blockDim.x + threadIdx.x;
  if (i < n) atomicAdd(&degi[dst[i]], 1);
}

// ---------------- scan (row_ptr build) ----------------
__global__ __launch_bounds__(1024) void scan1(const int* __restrict__ cnt,
                                              int* __restrict__ incl,
                                              int* __restrict__ bsum, int n) {
  __shared__ int s[1024];
  int tid = threadIdx.x;
  int i = blockIdx.x * 1024 + tid;
  int v = (i < n) ? cnt[i] : 0;
  s[tid] = v;
  __syncthreads();
  for (int off = 1; off < 1024; off <<= 1) {
    int t = (tid >= off) ? s[tid - off] : 0;
    __syncthreads();
    s[tid] += t;
    __syncthreads();
  }
  if (i < n) incl[i] = s[tid];
  if (tid == 1023) bsum[blockIdx.x] = s[1023];
}

__global__ void scan2(int* __restrict__ bsum, int nb) {
  int lane = threadIdx.x;  // single wave of 64
  int v = (lane < nb) ? bsum[lane] : 0;
  int orig = v;
  for (int off = 1; off < 64; off <<= 1) {
    int t = __shfl_up(v, off, 64);
    if (lane >= off) v += t;
  }
  if (lane < nb) bsum[lane] = v - orig;  // exclusive block offset
}

// scan3 + fused dinv compute
__global__ __launch_bounds__(1024) void scan3(const int* __restrict__ cnt,
                                              const int* __restrict__ incl,
                                              const int* __restrict__ bsum,
                                              int* __restrict__ rp,
                                              int* __restrict__ cursor,
                                              float* __restrict__ dinv, int n) {
  int tid = threadIdx.x;
  int i = blockIdx.x * 1024 + tid;
  if (i < n) {
    int v = incl[i] + bsum[blockIdx.x];
    rp[i + 1] = v;
    cursor[i] = v - cnt[i];
    dinv[i] = rsqrtf((float)(cnt[i] + 1));  // +1 self loop
  }
  if (i == 0) rp[0] = 0;
}

__global__ void fill_kernel(const int* __restrict__ src, const int* __restrict__ dst,
                            int* __restrict__ cursor, int* __restrict__ col, int n) {
  int i = blockIdx.x * blockDim.x + threadIdx.x;
  if (i < n) {
    int pos = atomicAdd(&cursor[dst[i]], 1);
    col[pos] = src[i];
  }
}

// ---------------- fused weight transpose + split (all 4 layers) ----------------
// [K][N] f32 -> [N][K] bf16 hi/lo
__device__ __forceinline__ void wsplit_one(const float* W, __bf16* th, __bf16* tl,
                                           int j, int K, int N) {
  int k = j / N, n = j - k * N;
  float v = W[j];
  __bf16 h = (__bf16)v;
  th[(size_t)n * K + k] = h;
  tl[(size_t)n * K + k] = (__bf16)(v - (float)h);
}

__global__ void wsplit_all(const float* __restrict__ W1, __bf16* t1h, __bf16* t1l,
                           const float* __restrict__ W2, __bf16* t2h, __bf16* t2l,
                           const float* __restrict__ W3, __bf16* t3h, __bf16* t3l,
                           const float* __restrict__ W4, __bf16* t4h, __bf16* t4l) {
  int i = blockIdx.x * blockDim.x + threadIdx.x;
  if (i < 32768) wsplit_one(W1, t1h, t1l, i, 128, 256);
  else if (i < 65536) wsplit_one(W2, t2h, t2l, i - 32768, 256, 128);
  else if (i < 73728) wsplit_one(W3, t3h, t3l, i - 65536, 128, 64);
  else if (i < 74112) wsplit_one(W4, t4h, t4l, i - 73728, 64, 6);
}

// ---------------- prescale to fp16: Xh[v][128] = x[v][:]*dinv[v] ----------------
__global__ void scale_half(const float* __restrict__ x, const float* __restrict__ dinv,
                           __half* __restrict__ o, int n4) {
  int i = blockIdx.x * blockDim.x + threadIdx.x;  // float4 index
  if (i >= n4) return;
  int v = i >> 5;  // 32 float4 per row
  float4 t = ((const float4*)x)[i];
  float s = dinv[v];
  __half2 a = __floats2half2_rn(t.x * s, t.y * s);
  __half2 b = __floats2half2_rn(t.z * s, t.w * s);
  __half2* o2 = (__half2*)o;
  o2[i * 2] = a;
  o2[i * 2 + 1] = b;
}

// ---------------- propagation (pull over CSR), fp16 gather planes ----------------
// One wave per node; input rows are fp16, prescaled by dinv[src].
// F=128: 2 features/lane (half2 loads). F=64: 1 feature/lane (ushort loads).
// f32 accumulate; EPI 0 = *dinv[v]; 1 = *dinv[v]+bias+BN+ReLU.
// Output: bf16 hi/lo planes for the following split-3 MFMA GEMM.
template <int F, int EPI>
__global__ __launch_bounds__(256, 8) void prop_half(
    const __half* __restrict__ in, const int* __restrict__ rp, const int* __restrict__ col,
    const float* __restrict__ dinv, const float* __restrict__ bias,
    const float* __restrict__ gam, const float* __restrict__ bet,
    const float* __restrict__ mean, const float* __restrict__ var,
    __bf16* __restrict__ out_hi, __bf16* __restrict__ out_lo, int nnodes) {
  int tid = threadIdx.x;
  int wid = tid >> 6, lane = tid & 63;
  constexpr int VEC = F / 64;  // 2 for F=128, 1 for F=64
  int v = blockIdx.x * 4 + wid;
  if (v >= nnodes) return;
  int e0 = rp[v], e1 = rp[v + 1];
  float acc[VEC];
  if constexpr (VEC == 2) {
    float2 f = __half22float2(*(const __half2*)(in + (size_t)v * F + lane * 2));
    acc[0] = f.x; acc[1] = f.y;
  } else {
    acc[0] = __half2float(in[(size_t)v * F + lane]);
  }
  int e1m1 = e1 - 1;
  constexpr int D = 8;
  for (int e = e0; e < e1; e += D) {
    int ss[D];
    float w[D];
    bool full = (e + D <= e1);
    if (full) {
#pragma unroll
      for (int u = 0; u < D; u++) { ss[u] = col[e + u]; w[u] = 1.f; }
    } else {
#pragma unroll
      for (int u = 0; u < D; u++) {
        int ei = e + u;
        ss[u] = col[ei < e1m1 ? ei : e1m1];
        w[u] = (ei < e1) ? 1.f : 0.f;
      }
    }
    if constexpr (VEC == 2) {
      __half2 hv[D];
#pragma unroll
      for (int u = 0; u < D; u++)
        hv[u] = *(const __half2*)(in + (size_t)ss[u] * F + lane * 2);
#pragma unroll
      for (int u = 0; u < D; u++) {
        float2 f = __half22float2(hv[u]);
        acc[0] = fmaf(f.x, w[u], acc[0]);
        acc[1] = fmaf(f.y, w[u], acc[1]);
      }
    } else {
      __half hv[D];
#pragma unroll
      for (int u = 0; u < D; u++) hv[u] = in[(size_t)ss[u] * F + lane];
#pragma unroll
      for (int u = 0; u < D; u++) acc[0] = fmaf(__half2float(hv[u]), w[u], acc[0]);
    }
  }
  float dv = dinv[v];
#pragma unroll
  for (int j = 0; j < VEC; j++) {
    int f = lane * VEC + j;
    float t = acc[j] * dv;
    if constexpr (EPI >= 1) {
      t += bias[f];
      t = (t - mean[f]) * rsqrtf(var[f] + EPS) * gam[f] + bet[f];
      t = fmaxf(t, 0.f);
    }
    __bf16 h = (__bf16)t;
    out_hi[(size_t)v * F + f] = h;
    out_lo[(size_t)v * F + f] = (__bf16)(t - (float)h);
  }
}

// ---------------- final prop (F=6), f32 input ----------------
__global__ __launch_bounds__(256, 8) void prop_small(
    const float* __restrict__ in, const int* __restrict__ rp, const int* __restrict__ col,
    const float* __restrict__ dinv, const float* __restrict__ bias,
    float* __restrict__ out, int nnodes) {
  constexpr int F = 6;
  int tid = threadIdx.x;
  int wid = tid >> 6, lane = tid & 63;
  int g = lane >> 3, f = lane & 7;
  int v = (blockIdx.x * 4 + wid) * 8 + g;
  if (v >= nnodes || f >= F) return;
  int e0 = rp[v], e1 = rp[v + 1];
  float acc = in[(size_t)v * F + f];
  int e1m1 = e1 - 1;
  constexpr int D = 8;
  for (int e = e0; e < e1; e += D) {
    int ss[D];
    float w[D];
#pragma unroll
    for (int u = 0; u < D; u++) {
      int ei = e + u;
      ss[u] = col[ei < e1m1 ? ei : e1m1];
      w[u] = (ei < e1) ? 1.0f : 0.0f;
    }
#pragma unroll
    for (int u = 0; u < D; u++) acc = fmaf(in[(size_t)ss[u] * F + f], w[u], acc);
  }
  out[(size_t)v * F + f] = acc * dinv[v] + bias[f];
}

// ---------------- MFMA GEMM (bf16 split-3), 128xBN tile, 4 waves ----------------
// A as hi/lo planes [M][K]; B as transposed hi/lo planes [N][K].
// EPI 0: +bias, BN, ReLU -> bf16 hi/lo planes.
// EPI 1: *dinv[row] -> fp16 plane (next prop's gather input).
// EPI 2: *dinv[row] -> f32 (final small layer).
template <int BN, int EPI>
__global__ __launch_bounds__(256, 4) void mfma_gemm(
    const __bf16* __restrict__ Ahi, const __bf16* __restrict__ Alo,
    const __bf16* __restrict__ Bhi, const __bf16* __restrict__ Blo,
    const float* __restrict__ bias, const float* __restrict__ gam,
    const float* __restrict__ bet, const float* __restrict__ mean,
    const float* __restrict__ var, const float* __restrict__ dinv,
    float* __restrict__ Cf, __half* __restrict__ Ch,
    __bf16* __restrict__ Chi, __bf16* __restrict__ Clo,
    int M, int K, int N) {
  constexpr int BM = 128, BK = 32, NB = BN / 16;
  // +8 bf16 pad (16 B): row stride 80 B spreads b128 frag reads across all 32 banks
  __shared__ __bf16 Ah[BM][BK + 8], Al[BM][BK + 8];
  __shared__ __bf16 Bh[BN][BK + 8], Bl[BN][BK + 8];
  int tid = threadIdx.x;
  int wid = tid >> 6, lane = tid & 63;
  int lr = lane & 15, lg = lane >> 4;
  int bm = blockIdx.x * BM, bn = blockIdx.y * BN;
  f32x4 acc[2][NB] = {};
  for (int k0 = 0; k0 < K; k0 += BK) {
#pragma unroll
    for (int c = 0; c < 2; c++) {  // A tile: 128 rows x 32 bf16, 16B chunks
      int idx = tid + c * 256;
      int r = idx >> 2, s = idx & 3;
      int rg = bm + r;
      uint4 vh = {0, 0, 0, 0}, vl = {0, 0, 0, 0};
      if (rg < M) {
        size_t go = (size_t)rg * K + k0 + s * 8;
        vh = *reinterpret_cast<const uint4*>(Ahi + go);
        vl = *reinterpret_cast<const uint4*>(Alo + go);
      }
      *reinterpret_cast<uint4*>(&Ah[r][s * 8]) = vh;
      *reinterpret_cast<uint4*>(&Al[r][s * 8]) = vl;
    }
#pragma unroll
    for (int c = 0; c < (BN * 4 + 255) / 256; c++) {  // B tile: BN rows x 32 bf16
      int idx = tid + c * 256;
      if (idx < BN * 4) {
        int r = idx >> 2, s = idx & 3;
        int rg = bn + r;
        uint4 vh = {0, 0, 0, 0}, vl = {0, 0, 0, 0};
        if (rg < N) {
          size_t go = (size_t)rg * K + k0 + s * 8;
          vh = *reinterpret_cast<const uint4*>(Bhi + go);
          vl = *reinterpret_cast<const uint4*>(Blo + go);
        }
        *reinterpret_cast<uint4*>(&Bh[r][s * 8]) = vh;
        *reinterpret_cast<uint4*>(&Bl[r][s * 8]) = vl;
      }
    }
    __syncthreads();
    int ar = wid * 32 + lr;
    bf16x8 ah0 = *reinterpret_cast<const bf16x8*>(&Ah[ar][lg * 8]);
    bf16x8 ah1 = *reinterpret_cast<const bf16x8*>(&Ah[ar + 16][lg * 8]);
    bf16x8 al0 = *reinterpret_cast<const bf16x8*>(&Al[ar][lg * 8]);
    bf16x8 al1 = *reinterpret_cast<const bf16x8*>(&Al[ar + 16][lg * 8]);
#pragma unroll
    for (int n = 0; n < NB; n++) {
      bf16x8 bh = *reinterpret_cast<const bf16x8*>(&Bh[n * 16 + lr][lg * 8]);
      bf16x8 bl = *reinterpret_cast<const bf16x8*>(&Bl[n * 16 + lr][lg * 8]);
      acc[0][n] = __builtin_amdgcn_mfma_f32_16x16x32_bf16(ah0, bh, acc[0][n], 0, 0, 0);
      acc[1][n] = __builtin_amdgcn_mfma_f32_16x16x32_bf16(ah1, bh, acc[1][n], 0, 0, 0);
      acc[0][n] = __builtin_amdgcn_mfma_f32_16x16x32_bf16(ah0, bl, acc[0][n], 0, 0, 0);
      acc[1][n] = __builtin_amdgcn_mfma_f32_16x16x32_bf16(ah1, bl, acc[1][n], 0, 0, 0);
      acc[0][n] = __builtin_amdgcn_mfma_f32_16x16x32_bf16(al0, bh, acc[0][n], 0, 0, 0);
      acc[1][n] = __builtin_amdgcn_mfma_f32_16x16x32_bf16(al1, bh, acc[1][n], 0, 0, 0);
    }
    __syncthreads();
  }
  // epilogue: C/D layout col=lane&15, row=(lane>>4)*4+reg (m89-verified)
#pragma unroll
  for (int m = 0; m < 2; m++) {
    int row0 = bm + wid * 32 + m * 16 + lg * 4;
#pragma unroll
    for (int n = 0; n < NB; n++) {
      int colg = bn + n * 16 + lr;
#pragma unroll
      for (int r = 0; r < 4; r++) {
        int row = row0 + r;
        if (row >= M) continue;
        float t = acc[m][n][r];
        if constexpr (EPI == 0) {
          t += bias[colg];
          t = (t - mean[colg]) * rsqrtf(var[colg] + EPS) * gam[colg] + bet[colg];
          t = fmaxf(t, 0.f);
          __bf16 h = (__bf16)t;
          Chi[(size_t)row * N + colg] = h;
          Clo[(size_t)row * N + colg] = (__bf16)(t - (float)h);
        } else if constexpr (EPI == 1) {
          Ch[(size_t)row * N + colg] = __float2half(t * dinv[row]);
        } else {
          if (colg < N) Cf[(size_t)row * N + colg] = t * dinv[row];
        }
      }
    }
  }
}

// ---------------- launch ----------------
extern "C" void kernel_launch(void* const* d_in, const int* in_sizes, int n_in,
                              void* d_out, int out_size, void* d_ws, size_t ws_size,
                              hipStream_t stream) {
  const float* x = (const float*)d_in[0];
  const int* ei = (const int*)d_in[1];
  const int* esrc = ei;
  const int* edst = ei + NE;
  const float* W1 = (const float*)d_in[2];  const float* b1 = (const float*)d_in[3];
  const float* g1 = (const float*)d_in[4];  const float* be1 = (const float*)d_in[5];
  const float* m1 = (const float*)d_in[6];  const float* v1 = (const float*)d_in[7];
  const float* W2 = (const float*)d_in[8];  const float* b2 = (const float*)d_in[9];
  const float* g2 = (const float*)d_in[10]; const float* be2 = (const float*)d_in[11];
  const float* m2 = (const float*)d_in[12]; const float* v2 = (const float*)d_in[13];
  const float* W3 = (const float*)d_in[14]; const float* b3 = (const float*)d_in[15];
  const float* g3 = (const float*)d_in[16]; const float* be3 = (const float*)d_in[17];
  const float* m3 = (const float*)d_in[18]; const float* v3 = (const float*)d_in[19];
  const float* W4 = (const float*)d_in[20]; const float* b4 = (const float*)d_in[21];
  float* out = (float*)d_out;

  // workspace layout
  char* base = (char*)d_ws;
  size_t off = 0;
  auto alloc = [&](size_t bytes) {
    void* p = base + off;
    off = (off + bytes + 255) & ~(size_t)255;
    return p;
  };
  __half* Xh = (__half*)alloc((size_t)NN * 128 * 2);      // fp16 gather plane (<=128 cols)
  float* F1 = (float*)alloc((size_t)NN * 6 * 4);          // f32 pre-final activations
  __bf16* PAh = (__bf16*)alloc((size_t)NN * 128 * 2);     // A planes (<=128 cols)
  __bf16* PAl = (__bf16*)alloc((size_t)NN * 128 * 2);
  __bf16* PHh = (__bf16*)alloc((size_t)NN * 256 * 2);     // h planes (<=256 cols)
  __bf16* PHl = (__bf16*)alloc((size_t)NN * 256 * 2);
  __bf16* Wt1h = (__bf16*)alloc(128 * 256 * 2); __bf16* Wt1l = (__bf16*)alloc(128 * 256 * 2);
  __bf16* Wt2h = (__bf16*)alloc(256 * 128 * 2); __bf16* Wt2l = (__bf16*)alloc(256 * 128 * 2);
  __bf16* Wt3h = (__bf16*)alloc(128 * 64 * 2);  __bf16* Wt3l = (__bf16*)alloc(128 * 64 * 2);
  __bf16* Wt4h = (__bf16*)alloc(64 * 6 * 2);    __bf16* Wt4l = (__bf16*)alloc(64 * 6 * 2);
  int* degi = (int*)alloc((size_t)NN * 4);
  float* dinv = (float*)alloc((size_t)NN * 4);
  int* rp = (int*)alloc((size_t)(NN + 1) * 4);
  int* cursor = (int*)alloc((size_t)NN * 4);
  int* incl = (int*)alloc((size_t)NN * 4);
  int* bsum = (int*)alloc(64 * 4);
  int* col = (int*)alloc((size_t)NE * 4);

  const int nBlkN = (NN + 255) / 256;
  const int nBlkE = (NE + 255) / 256;
  const int nBlkScan = (NN + 1023) / 1024;  // 49
  const int gM = (NN + 127) / 128;          // 391
  const int gP = (NN + 3) / 4;              // 12500

  // degree + CSR build (dinv fused into scan3)
  memset_i32<<<nBlkN, 256, 0, stream>>>(degi, NN);
  deg_kernel<<<nBlkE, 256, 0, stream>>>(edst, degi, NE);
  scan1<<<nBlkScan, 1024, 0, stream>>>(degi, incl, bsum, NN);
  scan2<<<1, 64, 0, stream>>>(bsum, nBlkScan);
  scan3<<<nBlkScan, 1024, 0, stream>>>(degi, incl, bsum, rp, cursor, dinv, NN);
  fill_kernel<<<nBlkE, 256, 0, stream>>>(esrc, edst, cursor, col, NE);

  // fused weight transpose+split (74112 elems)
  wsplit_all<<<(74112 + 255) / 256, 256, 0, stream>>>(W1, Wt1h, Wt1l, W2, Wt2h, Wt2l,
                                                      W3, Wt3h, Wt3l, W4, Wt4h, Wt4l);

  // ---- layer 1: prescale->fp16, prop(128), GEMM1(+b1,BN1,ReLU -> bf16 planes) ----
  scale_half<<<(NN * 32 + 255) / 256, 256, 0, stream>>>(x, dinv, Xh, NN * 32);
  prop_half<128, 0><<<gP, 256, 0, stream>>>(Xh, rp, col, dinv, nullptr, nullptr, nullptr,
                                            nullptr, nullptr, PAh, PAl, NN);
  {
    dim3 g(gM, 2);
    mfma_gemm<128, 0><<<g, 256, 0, stream>>>(PAh, PAl, Wt1h, Wt1l, b1, g1, be1, m1, v1,
                                             nullptr, nullptr, nullptr, PHh, PHl,
                                             NN, 128, 256);
  }
  // ---- layer 2: GEMM2(*dinv -> fp16), prop(128, +b2,BN2,ReLU -> bf16 planes) ----
  {
    dim3 g(gM, 1);
    mfma_gemm<128, 1><<<g, 256, 0, stream>>>(PHh, PHl, Wt2h, Wt2l, nullptr, nullptr,
                                             nullptr, nullptr, nullptr, dinv,
                                             nullptr, Xh, nullptr, nullptr, NN, 256, 128);
  }
  prop_half<128, 1><<<gP, 256, 0, stream>>>(Xh, rp, col, dinv, b2, g2, be2, m2, v2,
                                            PAh, PAl, NN);
  // ---- layer 3: GEMM3(*dinv -> fp16), prop(64, +b3,BN3,ReLU -> bf16 planes) ----
  {
    dim3 g(gM, 1);
    mfma_gemm<64, 1><<<g, 256, 0, stream>>>(PAh, PAl, Wt3h, Wt3l, nullptr, nullptr,
                                            nullptr, nullptr, nullptr, dinv,
                                            nullptr, Xh, nullptr, nullptr, NN, 128, 64);
  }
  prop_half<64, 1><<<gP, 256, 0, stream>>>(Xh, rp, col, dinv, b3, g3, be3, m3, v3,
                                           PHh, PHl, NN);
  // ---- layer 4: GEMM4(*dinv -> f32, N=6), final prop (+b4) ----
  {
    dim3 g(gM, 1);
    mfma_gemm<16, 2><<<g, 256, 0, stream>>>(PHh, PHl, Wt4h, Wt4l, nullptr, nullptr,
                                            nullptr, nullptr, nullptr, dinv,
                                            F1, nullptr, nullptr, nullptr, NN, 64, 6);
  }
  prop_small<<<(NN + 31) / 32, 256, 0, stream>>>(F1, rp, col, dinv, b4, out, NN);
}

// Round 10
// 287.612 us; speedup vs baseline: 1.7707x; 1.0066x over previous
//
#include <hip/hip_runtime.h>
#include <hip/hip_bf16.h>
#include <hip/hip_fp16.h>

#define EPS 1e-5f

constexpr int NN = 50000;   // nodes
constexpr int NE = 800000;  // edges

typedef __attribute__((ext_vector_type(8))) __bf16 bf16x8;
typedef __attribute__((ext_vector_type(4))) float f32x4;

// ---------------- utility kernels ----------------
__global__ void memset_i32(int* p, int n) {
  int i = blockIdx.x * blockDim.x + threadIdx.x;
  if (i < n) p[i] = 0;
}

__global__ void deg_kernel(const int* __restrict__ dst, int* __restrict__ degi, int n) {
  int i = blockIdx.x * blockDim.x + threadIdx.x;
  if (i < n) atomicAdd(&degi[dst[i]], 1);
}

// ---------------- scan (row_ptr build) ----------------
__global__ __launch_bounds__(1024) void scan1(const int* __restrict__ cnt,
                                              int* __restrict__ incl,
                                              int* __restrict__ bsum, int n) {
  __shared__ int s[1024];
  int tid = threadIdx.x;
  int i = blockIdx.x * 1024 + tid;
  int v = (i < n) ? cnt[i] : 0;
  s[tid] = v;
  __syncthreads();
  for (int off = 1; off < 1024; off <<= 1) {
    int t = (tid >= off) ? s[tid - off] : 0;
    __syncthreads();
    s[tid] += t;
    __syncthreads();
  }
  if (i < n) incl[i] = s[tid];
  if (tid == 1023) bsum[blockIdx.x] = s[1023];
}

__global__ void scan2(int* __restrict__ bsum, int nb) {
  int lane = threadIdx.x;  // single wave of 64
  int v = (lane < nb) ? bsum[lane] : 0;
  int orig = v;
  for (int off = 1; off < 64; off <<= 1) {
    int t = __shfl_up(v, off, 64);
    if (lane >= off) v += t;
  }
  if (lane < nb) bsum[lane] = v - orig;  // exclusive block offset
}

// scan3 + fused dinv compute
__global__ __launch_bounds__(1024) void scan3(const int* __restrict__ cnt,
                                              const int* __restrict__ incl,
                                              const int* __restrict__ bsum,
                                              int* __restrict__ rp,
                                              int* __restrict__ cursor,
                                              float* __restrict__ dinv, int n) {
  int tid = threadIdx.x;
  int i = blockIdx.x * 1024 + tid;
  if (i < n) {
    int v = incl[i] + bsum[blockIdx.x];
    rp[i + 1] = v;
    cursor[i] = v - cnt[i];
    dinv[i] = rsqrtf((float)(cnt[i] + 1));  // +1 self loop
  }
  if (i == 0) rp[0] = 0;
}

// col as uint16 (node ids < 65536): 1.6MB array stays L2-resident during the
// random fill -> line writebacks collapse (52MB -> ~13MB write traffic)
__global__ void fill_kernel(const int* __restrict__ src, const int* __restrict__ dst,
                            int* __restrict__ cursor, unsigned short* __restrict__ col,
                            int n) {
  int i = blockIdx.x * blockDim.x + threadIdx.x;
  if (i < n) {
    int pos = atomicAdd(&cursor[dst[i]], 1);
    col[pos] = (unsigned short)src[i];
  }
}

// ---------------- fused weight transpose + split (all 4 layers) ----------------
// [K][N] f32 -> [N][K] bf16 hi/lo
__device__ __forceinline__ void wsplit_one(const float* W, __bf16* th, __bf16* tl,
                                           int j, int K, int N) {
  int k = j / N, n = j - k * N;
  float v = W[j];
  __bf16 h = (__bf16)v;
  th[(size_t)n * K + k] = h;
  tl[(size_t)n * K + k] = (__bf16)(v - (float)h);
}

__global__ void wsplit_all(const float* __restrict__ W1, __bf16* t1h, __bf16* t1l,
                           const float* __restrict__ W2, __bf16* t2h, __bf16* t2l,
                           const float* __restrict__ W3, __bf16* t3h, __bf16* t3l,
                           const float* __restrict__ W4, __bf16* t4h, __bf16* t4l) {
  int i = blockIdx.x * blockDim.x + threadIdx.x;
  if (i < 32768) wsplit_one(W1, t1h, t1l, i, 128, 256);
  else if (i < 65536) wsplit_one(W2, t2h, t2l, i - 32768, 256, 128);
  else if (i < 73728) wsplit_one(W3, t3h, t3l, i - 65536, 128, 64);
  else if (i < 74112) wsplit_one(W4, t4h, t4l, i - 73728, 64, 6);
}

// ---------------- prescale to fp16: Xh[v][128] = x[v][:]*dinv[v] ----------------
__global__ void scale_half(const float* __restrict__ x, const float* __restrict__ dinv,
                           __half* __restrict__ o, int n4) {
  int i = blockIdx.x * blockDim.x + threadIdx.x;  // float4 index
  if (i >= n4) return;
  int v = i >> 5;  // 32 float4 per row
  float4 t = ((const float4*)x)[i];
  float s = dinv[v];
  __half2 a = __floats2half2_rn(t.x * s, t.y * s);
  __half2 b = __floats2half2_rn(t.z * s, t.w * s);
  __half2* o2 = (__half2*)o;
  o2[i * 2] = a;
  o2[i * 2 + 1] = b;
}

// ---------------- propagation (pull over CSR), fp16 gather planes ----------------
// One wave per node; input rows are fp16, prescaled by dinv[src].
// F=128: 2 features/lane (half2 loads). F=64: 1 feature/lane.
// f32 accumulate; EPI 0 = *dinv[v]; 1 = *dinv[v]+bias+BN+ReLU.
// Output: bf16 hi/lo planes for the following split-3 MFMA GEMM.
template <int F, int EPI>
__global__ __launch_bounds__(256, 8) void prop_half(
    const __half* __restrict__ in, const int* __restrict__ rp,
    const unsigned short* __restrict__ col,
    const float* __restrict__ dinv, const float* __restrict__ bias,
    const float* __restrict__ gam, const float* __restrict__ bet,
    const float* __restrict__ mean, const float* __restrict__ var,
    __bf16* __restrict__ out_hi, __bf16* __restrict__ out_lo, int nnodes) {
  int tid = threadIdx.x;
  int wid = tid >> 6, lane = tid & 63;
  constexpr int VEC = F / 64;  // 2 for F=128, 1 for F=64
  int v = blockIdx.x * 4 + wid;
  if (v >= nnodes) return;
  int e0 = rp[v], e1 = rp[v + 1];
  float acc[VEC];
  if constexpr (VEC == 2) {
    float2 f = __half22float2(*(const __half2*)(in + (size_t)v * F + lane * 2));
    acc[0] = f.x; acc[1] = f.y;
  } else {
    acc[0] = __half2float(in[(size_t)v * F + lane]);
  }
  int e1m1 = e1 - 1;
  constexpr int D = 8;
  for (int e = e0; e < e1; e += D) {
    int ss[D];
    float w[D];
    bool full = (e + D <= e1);
    if (full) {
#pragma unroll
      for (int u = 0; u < D; u++) { ss[u] = col[e + u]; w[u] = 1.f; }
    } else {
#pragma unroll
      for (int u = 0; u < D; u++) {
        int ei = e + u;
        ss[u] = col[ei < e1m1 ? ei : e1m1];
        w[u] = (ei < e1) ? 1.f : 0.f;
      }
    }
    if constexpr (VEC == 2) {
      __half2 hv[D];
#pragma unroll
      for (int u = 0; u < D; u++)
        hv[u] = *(const __half2*)(in + (size_t)ss[u] * F + lane * 2);
#pragma unroll
      for (int u = 0; u < D; u++) {
        float2 f = __half22float2(hv[u]);
        acc[0] = fmaf(f.x, w[u], acc[0]);
        acc[1] = fmaf(f.y, w[u], acc[1]);
      }
    } else {
      __half hv[D];
#pragma unroll
      for (int u = 0; u < D; u++) hv[u] = in[(size_t)ss[u] * F + lane];
#pragma unroll
      for (int u = 0; u < D; u++) acc[0] = fmaf(__half2float(hv[u]), w[u], acc[0]);
    }
  }
  float dv = dinv[v];
#pragma unroll
  for (int j = 0; j < VEC; j++) {
    int f = lane * VEC + j;
    float t = acc[j] * dv;
    if constexpr (EPI >= 1) {
      t += bias[f];
      t = (t - mean[f]) * rsqrtf(var[f] + EPS) * gam[f] + bet[f];
      t = fmaxf(t, 0.f);
    }
    __bf16 h = (__bf16)t;
    out_hi[(size_t)v * F + f] = h;
    out_lo[(size_t)v * F + f] = (__bf16)(t - (float)h);
  }
}

// ---------------- final prop (F=6), f32 input ----------------
__global__ __launch_bounds__(256, 8) void prop_small(
    const float* __restrict__ in, const int* __restrict__ rp,
    const unsigned short* __restrict__ col,
    const float* __restrict__ dinv, const float* __restrict__ bias,
    float* __restrict__ out, int nnodes) {
  constexpr int F = 6;
  int tid = threadIdx.x;
  int wid = tid >> 6, lane = tid & 63;
  int g = lane >> 3, f = lane & 7;
  int v = (blockIdx.x * 4 + wid) * 8 + g;
  if (v >= nnodes || f >= F) return;
  int e0 = rp[v], e1 = rp[v + 1];
  float acc = in[(size_t)v * F + f];
  int e1m1 = e1 - 1;
  constexpr int D = 8;
  for (int e = e0; e < e1; e += D) {
    int ss[D];
    float w[D];
#pragma unroll
    for (int u = 0; u < D; u++) {
      int ei = e + u;
      ss[u] = col[ei < e1m1 ? ei : e1m1];
      w[u] = (ei < e1) ? 1.0f : 0.0f;
    }
#pragma unroll
    for (int u = 0; u < D; u++) acc = fmaf(in[(size_t)ss[u] * F + f], w[u], acc);
  }
  out[(size_t)v * F + f] = acc * dinv[v] + bias[f];
}

// ---------------- MFMA GEMM (bf16 split-3), 128xBN tile, 4 waves ----------------
// A as hi/lo planes [M][K]; B as transposed hi/lo planes [N][K].
// EPI 0: +bias, BN, ReLU -> bf16 hi/lo planes.
// EPI 1: *dinv[row] -> fp16 plane (next prop's gather input).
// EPI 2: *dinv[row] -> f32 (final small layer).
template <int BN, int EPI>
__global__ __launch_bounds__(256, 4) void mfma_gemm(
    const __bf16* __restrict__ Ahi, const __bf16* __restrict__ Alo,
    const __bf16* __restrict__ Bhi, const __bf16* __restrict__ Blo,
    const float* __restrict__ bias, const float* __restrict__ gam,
    const float* __restrict__ bet, const float* __restrict__ mean,
    const float* __restrict__ var, const float* __restrict__ dinv,
    float* __restrict__ Cf, __half* __restrict__ Ch,
    __bf16* __restrict__ Chi, __bf16* __restrict__ Clo,
    int M, int K, int N) {
  constexpr int BM = 128, BK = 32, NB = BN / 16;
  // +8 bf16 pad (16 B): row stride 80 B spreads b128 frag reads across all 32 banks
  __shared__ __bf16 Ah[BM][BK + 8], Al[BM][BK + 8];
  __shared__ __bf16 Bh[BN][BK + 8], Bl[BN][BK + 8];
  int tid = threadIdx.x;
  int wid = tid >> 6, lane = tid & 63;
  int lr = lane & 15, lg = lane >> 4;
  int bm = blockIdx.x * BM, bn = blockIdx.y * BN;
  f32x4 acc[2][NB] = {};
  for (int k0 = 0; k0 < K; k0 += BK) {
#pragma unroll
    for (int c = 0; c < 2; c++) {  // A tile: 128 rows x 32 bf16, 16B chunks
      int idx = tid + c * 256;
      int r = idx >> 2, s = idx & 3;
      int rg = bm + r;
      uint4 vh = {0, 0, 0, 0}, vl = {0, 0, 0, 0};
      if (rg < M) {
        size_t go = (size_t)rg * K + k0 + s * 8;
        vh = *reinterpret_cast<const uint4*>(Ahi + go);
        vl = *reinterpret_cast<const uint4*>(Alo + go);
      }
      *reinterpret_cast<uint4*>(&Ah[r][s * 8]) = vh;
      *reinterpret_cast<uint4*>(&Al[r][s * 8]) = vl;
    }
#pragma unroll
    for (int c = 0; c < (BN * 4 + 255) / 256; c++) {  // B tile: BN rows x 32 bf16
      int idx = tid + c * 256;
      if (idx < BN * 4) {
        int r = idx >> 2, s = idx & 3;
        int rg = bn + r;
        uint4 vh = {0, 0, 0, 0}, vl = {0, 0, 0, 0};
        if (rg < N) {
          size_t go = (size_t)rg * K + k0 + s * 8;
          vh = *reinterpret_cast<const uint4*>(Bhi + go);
          vl = *reinterpret_cast<const uint4*>(Blo + go);
        }
        *reinterpret_cast<uint4*>(&Bh[r][s * 8]) = vh;
        *reinterpret_cast<uint4*>(&Bl[r][s * 8]) = vl;
      }
    }
    __syncthreads();
    int ar = wid * 32 + lr;
    bf16x8 ah0 = *reinterpret_cast<const bf16x8*>(&Ah[ar][lg * 8]);
    bf16x8 ah1 = *reinterpret_cast<const bf16x8*>(&Ah[ar + 16][lg * 8]);
    bf16x8 al0 = *reinterpret_cast<const bf16x8*>(&Al[ar][lg * 8]);
    bf16x8 al1 = *reinterpret_cast<const bf16x8*>(&Al[ar + 16][lg * 8]);
#pragma unroll
    for (int n = 0; n < NB; n++) {
      bf16x8 bh = *reinterpret_cast<const bf16x8*>(&Bh[n * 16 + lr][lg * 8]);
      bf16x8 bl = *reinterpret_cast<const bf16x8*>(&Bl[n * 16 + lr][lg * 8]);
      acc[0][n] = __builtin_amdgcn_mfma_f32_16x16x32_bf16(ah0, bh, acc[0][n], 0, 0, 0);
      acc[1][n] = __builtin_amdgcn_mfma_f32_16x16x32_bf16(ah1, bh, acc[1][n], 0, 0, 0);
      acc[0][n] = __builtin_amdgcn_mfma_f32_16x16x32_bf16(ah0, bl, acc[0][n], 0, 0, 0);
      acc[1][n] = __builtin_amdgcn_mfma_f32_16x16x32_bf16(ah1, bl, acc[1][n], 0, 0, 0);
      acc[0][n] = __builtin_amdgcn_mfma_f32_16x16x32_bf16(al0, bh, acc[0][n], 0, 0, 0);
      acc[1][n] = __builtin_amdgcn_mfma_f32_16x16x32_bf16(al1, bh, acc[1][n], 0, 0, 0);
    }
    __syncthreads();
  }
  // epilogue: C/D layout col=lane&15, row=(lane>>4)*4+reg (m89-verified)
#pragma unroll
  for (int m = 0; m < 2; m++) {
    int row0 = bm + wid * 32 + m * 16 + lg * 4;
#pragma unroll
    for (int n = 0; n < NB; n++) {
      int colg = bn + n * 16 + lr;
#pragma unroll
      for (int r = 0; r < 4; r++) {
        int row = row0 + r;
        if (row >= M) continue;
        float t = acc[m][n][r];
        if constexpr (EPI == 0) {
          t += bias[colg];
          t = (t - mean[colg]) * rsqrtf(var[colg] + EPS) * gam[colg] + bet[colg];
          t = fmaxf(t, 0.f);
          __bf16 h = (__bf16)t;
          Chi[(size_t)row * N + colg] = h;
          Clo[(size_t)row * N + colg] = (__bf16)(t - (float)h);
        } else if constexpr (EPI == 1) {
          Ch[(size_t)row * N + colg] = __float2half(t * dinv[row]);
        } else {
          if (colg < N) Cf[(size_t)row * N + colg] = t * dinv[row];
        }
      }
    }
  }
}

// ---------------- launch ----------------
extern "C" void kernel_launch(void* const* d_in, const int* in_sizes, int n_in,
                              void* d_out, int out_size, void* d_ws, size_t ws_size,
                              hipStream_t stream) {
  const float* x = (const float*)d_in[0];
  const int* ei = (const int*)d_in[1];
  const int* esrc = ei;
  const int* edst = ei + NE;
  const float* W1 = (const float*)d_in[2];  const float* b1 = (const float*)d_in[3];
  const float* g1 = (const float*)d_in[4];  const float* be1 = (const float*)d_in[5];
  const float* m1 = (const float*)d_in[6];  const float* v1 = (const float*)d_in[7];
  const float* W2 = (const float*)d_in[8];  const float* b2 = (const float*)d_in[9];
  const float* g2 = (const float*)d_in[10]; const float* be2 = (const float*)d_in[11];
  const float* m2 = (const float*)d_in[12]; const float* v2 = (const float*)d_in[13];
  const float* W3 = (const float*)d_in[14]; const float* b3 = (const float*)d_in[15];
  const float* g3 = (const float*)d_in[16]; const float* be3 = (const float*)d_in[17];
  const float* m3 = (const float*)d_in[18]; const float* v3 = (const float*)d_in[19];
  const float* W4 = (const float*)d_in[20]; const float* b4 = (const float*)d_in[21];
  float* out = (float*)d_out;

  // workspace layout
  char* base = (char*)d_ws;
  size_t off = 0;
  auto alloc = [&](size_t bytes) {
    void* p = base + off;
    off = (off + bytes + 255) & ~(size_t)255;
    return p;
  };
  __half* Xh = (__half*)alloc((size_t)NN * 128 * 2);      // fp16 gather plane (<=128 cols)
  float* F1 = (float*)alloc((size_t)NN * 6 * 4);          // f32 pre-final activations
  __bf16* PAh = (__bf16*)alloc((size_t)NN * 128 * 2);     // A planes (<=128 cols)
  __bf16* PAl = (__bf16*)alloc((size_t)NN * 128 * 2);
  __bf16* PHh = (__bf16*)alloc((size_t)NN * 256 * 2);     // h planes (<=256 cols)
  __bf16* PHl = (__bf16*)alloc((size_t)NN * 256 * 2);
  __bf16* Wt1h = (__bf16*)alloc(128 * 256 * 2); __bf16* Wt1l = (__bf16*)alloc(128 * 256 * 2);
  __bf16* Wt2h = (__bf16*)alloc(256 * 128 * 2); __bf16* Wt2l = (__bf16*)alloc(256 * 128 * 2);
  __bf16* Wt3h = (__bf16*)alloc(128 * 64 * 2);  __bf16* Wt3l = (__bf16*)alloc(128 * 64 * 2);
  __bf16* Wt4h = (__bf16*)alloc(64 * 6 * 2);    __bf16* Wt4l = (__bf16*)alloc(64 * 6 * 2);
  int* degi = (int*)alloc((size_t)NN * 4);
  float* dinv = (float*)alloc((size_t)NN * 4);
  int* rp = (int*)alloc((size_t)(NN + 1) * 4);
  int* cursor = (int*)alloc((size_t)NN * 4);
  int* incl = (int*)alloc((size_t)NN * 4);
  int* bsum = (int*)alloc(64 * 4);
  unsigned short* col = (unsigned short*)alloc((size_t)NE * 2);

  const int nBlkN = (NN + 255) / 256;
  const int nBlkE = (NE + 255) / 256;
  const int nBlkScan = (NN + 1023) / 1024;  // 49
  const int gM = (NN + 127) / 128;          // 391
  const int gP = (NN + 3) / 4;              // 12500

  // degree + CSR build (dinv fused into scan3)
  memset_i32<<<nBlkN, 256, 0, stream>>>(degi, NN);
  deg_kernel<<<nBlkE, 256, 0, stream>>>(edst, degi, NE);
  scan1<<<nBlkScan, 1024, 0, stream>>>(degi, incl, bsum, NN);
  scan2<<<1, 64, 0, stream>>>(bsum, nBlkScan);
  scan3<<<nBlkScan, 1024, 0, stream>>>(degi, incl, bsum, rp, cursor, dinv, NN);
  fill_kernel<<<nBlkE, 256, 0, stream>>>(esrc, edst, cursor, col, NE);

  // fused weight transpose+split (74112 elems)
  wsplit_all<<<(74112 + 255) / 256, 256, 0, stream>>>(W1, Wt1h, Wt1l, W2, Wt2h, Wt2l,
                                                      W3, Wt3h, Wt3l, W4, Wt4h, Wt4l);

  // ---- layer 1: prescale->fp16, prop(128), GEMM1(+b1,BN1,ReLU -> bf16 planes) ----
  scale_half<<<(NN * 32 + 255) / 256, 256, 0, stream>>>(x, dinv, Xh, NN * 32);
  prop_half<128, 0><<<gP, 256, 0, stream>>>(Xh, rp, col, dinv, nullptr, nullptr, nullptr,
                                            nullptr, nullptr, PAh, PAl, NN);
  {
    dim3 g(gM, 2);
    mfma_gemm<128, 0><<<g, 256, 0, stream>>>(PAh, PAl, Wt1h, Wt1l, b1, g1, be1, m1, v1,
                                             nullptr, nullptr, nullptr, PHh, PHl,
                                             NN, 128, 256);
  }
  // ---- layer 2: GEMM2(*dinv -> fp16), prop(128, +b2,BN2,ReLU -> bf16 planes) ----
  {
    dim3 g(gM, 1);
    mfma_gemm<128, 1><<<g, 256, 0, stream>>>(PHh, PHl, Wt2h, Wt2l, nullptr, nullptr,
                                             nullptr, nullptr, nullptr, dinv,
                                             nullptr, Xh, nullptr, nullptr, NN, 256, 128);
  }
  prop_half<128, 1><<<gP, 256, 0, stream>>>(Xh, rp, col, dinv, b2, g2, be2, m2, v2,
                                            PAh, PAl, NN);
  // ---- layer 3: GEMM3(*dinv -> fp16), prop(64, +b3,BN3,ReLU -> bf16 planes) ----
  {
    dim3 g(gM, 1);
    mfma_gemm<64, 1><<<g, 256, 0, stream>>>(PAh, PAl, Wt3h, Wt3l, nullptr, nullptr,
                                            nullptr, nullptr, nullptr, dinv,
                                            nullptr, Xh, nullptr, nullptr, NN, 128, 64);
  }
  prop_half<64, 1><<<gP, 256, 0, stream>>>(Xh, rp, col, dinv, b3, g3, be3, m3, v3,
                                           PHh, PHl, NN);
  // ---- layer 4: GEMM4(*dinv -> f32, N=6), final prop (+b4) ----
  {
    dim3 g(gM, 1);
    mfma_gemm<16, 2><<<g, 256, 0, stream>>>(PHh, PHl, Wt4h, Wt4l, nullptr, nullptr,
                                            nullptr, nullptr, nullptr, dinv,
                                            F1, nullptr, nullptr, nullptr, NN, 64, 6);
  }
  prop_small<<<(NN + 31) / 32, 256, 0, stream>>>(F1, rp, col, dinv, b4, out, NN);
}